// Round 3
// baseline (948.400 us; speedup 1.0000x reference)
//
#include <hip/hip_runtime.h>
#include <hip/hip_bf16.h>

#define N_NODES 100000
#define N_EDGES 3200000
#define N_GRAPHS 512
#define HID 64
#define OUT_DIM 10

// ---------------------------------------------------------------------------
// K1: in-degree histogram over dst (4 edges/thread)
__global__ void k_deg(const int4* __restrict__ dst4, unsigned* __restrict__ cnt) {
    int e = blockIdx.x * blockDim.x + threadIdx.x;
    if (e < N_EDGES / 4) {
        int4 d = dst4[e];
        atomicAdd(&cnt[d.x], 1u);
        atomicAdd(&cnt[d.y], 1u);
        atomicAdd(&cnt[d.z], 1u);
        atomicAdd(&cnt[d.w], 1u);
    }
}

// K2: dinv = 1/sqrt(deg+1) (self loop), g1 = dinv*x
__global__ void k_dinv(const unsigned* __restrict__ cnt, const float* __restrict__ x,
                       float* __restrict__ dinv, float* __restrict__ g1) {
    int i = blockIdx.x * blockDim.x + threadIdx.x;
    if (i < N_NODES) {
        float d = 1.0f / sqrtf((float)cnt[i] + 1.0f);
        dinv[i] = d;
        g1[i] = d * x[i];
    }
}

// K3: single-block exclusive scan of cnt -> off; also seeds cursor = off.
__global__ __launch_bounds__(1024) void k_scan(const unsigned* __restrict__ cnt,
                                               int* __restrict__ off,
                                               unsigned* __restrict__ cursor) {
    __shared__ int part[1024];
    const int T = 1024;
    int t = threadIdx.x;
    const int chunk = (N_NODES + T - 1) / T;
    int lo = t * chunk;
    int hi = lo + chunk; if (hi > N_NODES) hi = N_NODES;
    int sacc = 0;
    for (int i = lo; i < hi; i++) sacc += (int)cnt[i];
    part[t] = sacc;
    __syncthreads();
    for (int d = 1; d < T; d <<= 1) {
        int v = (t >= d) ? part[t - d] : 0;
        __syncthreads();
        part[t] += v;
        __syncthreads();
    }
    int run = (t == 0) ? 0 : part[t - 1];
    for (int i = lo; i < hi; i++) {
        off[i] = run;
        cursor[i] = (unsigned)run;
        run += (int)cnt[i];
    }
    if (t == T - 1) off[N_NODES] = part[T - 1];
}

// K4: scatter edges into CSR by dst (absolute cursor) + fused layer-1 scalar
// aggregation: sacc[dst] += dinv[src]*x[src].  4 edges/thread.
__global__ void k_scatter(const int4* __restrict__ src4, const int4* __restrict__ dst4,
                          unsigned* __restrict__ cursor, int* __restrict__ csr,
                          const float* __restrict__ g1, float* __restrict__ sacc) {
    int e = blockIdx.x * blockDim.x + threadIdx.x;
    if (e >= N_EDGES / 4) return;
    int4 s = src4[e];
    int4 d = dst4[e];
    {
        unsigned p = atomicAdd(&cursor[d.x], 1u);
        csr[p] = s.x;
        atomicAdd(&sacc[d.x], g1[s.x]);
    }
    {
        unsigned p = atomicAdd(&cursor[d.y], 1u);
        csr[p] = s.y;
        atomicAdd(&sacc[d.y], g1[s.y]);
    }
    {
        unsigned p = atomicAdd(&cursor[d.z], 1u);
        csr[p] = s.z;
        atomicAdd(&sacc[d.z], g1[s.z]);
    }
    {
        unsigned p = atomicAdd(&cursor[d.w], 1u);
        csr[p] = s.w;
        atomicAdd(&sacc[d.w], g1[s.w]);
    }
}

// K5: finish layer 1: s = dinv*(sacc + dinv*x); store (s, dinv) pair.
__global__ void k_sd(const float* __restrict__ sacc, const float* __restrict__ dinv,
                     const float* __restrict__ x, float2* __restrict__ sd) {
    int i = blockIdx.x * blockDim.x + threadIdx.x;
    if (i < N_NODES) {
        float dn = dinv[i];
        float s = dn * (sacc[i] + dn * x[i]);
        sd[i] = make_float2(s, dn);
    }
}

// K6: layer-2 aggregation + fused x2 = relu(agg@W2+b2). One wave per node,
// lane j owns channel j. Edge (s,dinv) pairs are gathered lane-parallel, then
// broadcast via shuffles -> inner loop is pure VALU, no dependent loads.
__global__ __launch_bounds__(256) void k_layer2(const int* __restrict__ csr,
                                                const int* __restrict__ off,
                                                const float2* __restrict__ sd,
                                                const float* __restrict__ W1,
                                                const float* __restrict__ b1,
                                                const float* __restrict__ W2,
                                                const float* __restrict__ b2,
                                                float* __restrict__ x2out) {
    __shared__ float w2s[HID * HID];
    for (int i = threadIdx.x; i < HID * HID; i += blockDim.x) w2s[i] = W2[i];
    __syncthreads();
    int wid = (blockIdx.x * blockDim.x + threadIdx.x) >> 6;
    int lane = threadIdx.x & 63;
    if (wid >= N_NODES) return;
    wid = __builtin_amdgcn_readfirstlane(wid);
    float w = W1[lane], b = b1[lane];
    int lo = off[wid], hi = off[wid + 1];
    float acc = 0.f;
    for (int base = lo; base < hi; base += 64) {
        int n = hi - base; if (n > 64) n = 64;
        float2 v = make_float2(0.f, 0.f);
        if (base + lane < hi) v = sd[csr[base + lane]];
        for (int k = 0; k < n; k++) {
            float s  = __shfl(v.x, k, 64);
            float dn = __shfl(v.y, k, 64);
            float t = fmaxf(fmaf(s, w, b), 0.f);
            acc = fmaf(dn, t, acc);
        }
    }
    float2 self = sd[wid];
    {
        float t = fmaxf(fmaf(self.x, w, b), 0.f);
        acc = fmaf(self.y, t, acc);
    }
    float aggv = self.y * acc;                 // agg[wid][lane]
    // x2 = relu(agg @ W2 + b2): broadcast agg row across lanes
    float acc2 = b2[lane];
    #pragma unroll 8
    for (int k = 0; k < HID; k++) {
        float a = __shfl(aggv, k, 64);
        acc2 = fmaf(a, w2s[k * HID + lane], acc2);
    }
    x2out[(size_t)wid * HID + lane] = fmaxf(acc2, 0.f);
}

// K7: graph segment boundaries from sorted batch.
__global__ void k_bounds(const int* __restrict__ batch, int* __restrict__ gstart) {
    int i = blockIdx.x * blockDim.x + threadIdx.x;
    if (i >= N_NODES) return;
    int b = batch[i];
    if (i == 0) {
        for (int g = 0; g <= b; g++) gstart[g] = 0;
    } else {
        int pb = batch[i - 1];
        for (int g = pb + 1; g <= b; g++) gstart[g] = i;
    }
    if (i == N_NODES - 1) {
        for (int g = b + 1; g <= N_GRAPHS; g++) gstart[g] = N_NODES;
    }
}

// K8: fused mean-pool + linear head. One block (256 thr) per graph.
// c<64 accumulates x1[n][c] (recomputed from s); c>=64 accumulates x2[n][c-64];
// two node-partitions reduced through LDS.
__global__ __launch_bounds__(256) void k_pool(const float* __restrict__ x2,
                                              const float2* __restrict__ sd,
                                              const float* __restrict__ W1,
                                              const float* __restrict__ b1,
                                              const int* __restrict__ gstart,
                                              const float* __restrict__ Wl,
                                              const float* __restrict__ bl,
                                              float* __restrict__ out) {
    int g = blockIdx.x;
    int t = threadIdx.x;
    int c = t & 127;
    int part = t >> 7;
    int lo = gstart[g], hi = gstart[g + 1];
    float w = 0.f, b = 0.f;
    if (c < HID) { w = W1[c]; b = b1[c]; }
    float acc = 0.f;
    if (c < HID) {
        for (int n = lo + part; n < hi; n += 2)
            acc += fmaxf(fmaf(sd[n].x, w, b), 0.f);
    } else {
        int j = c - HID;
        for (int n = lo + part; n < hi; n += 2)
            acc += x2[(size_t)n * HID + j];
    }
    __shared__ float pl[2 * HID];
    if (part == 0) pl[c] = acc;
    __syncthreads();
    if (part == 1) pl[c] += acc;
    __syncthreads();
    if (t < 2 * HID) pl[t] /= fmaxf((float)(hi - lo), 1.f);
    __syncthreads();
    if (t < OUT_DIM) {
        float r = bl[t];
        #pragma unroll 16
        for (int j = 0; j < 2 * HID; j++) r = fmaf(pl[j], Wl[j * OUT_DIM + t], r);
        out[g * OUT_DIM + t] = r;
    }
}

// ---------------------------------------------------------------------------
extern "C" void kernel_launch(void* const* d_in, const int* in_sizes, int n_in,
                              void* d_out, int out_size, void* d_ws, size_t ws_size,
                              hipStream_t stream) {
    const float* x      = (const float*)d_in[0];
    const int*   ei     = (const int*)d_in[1];           // (2, E) int32
    const int*   batch  = (const int*)d_in[2];
    const float* W1     = (const float*)d_in[3];
    const float* b1     = (const float*)d_in[4];
    const float* W2     = (const float*)d_in[5];
    const float* b2     = (const float*)d_in[6];
    const float* Wl     = (const float*)d_in[7];
    const float* bl     = (const float*)d_in[8];
    float* out = (float*)d_out;

    const int* src = ei;
    const int* dst = ei + N_EDGES;

    // workspace carve-up (256B aligned)
    char* p = (char*)d_ws;
    auto alloc = [&](size_t bytes) { void* r = (void*)p; p += (bytes + 255) & ~(size_t)255; return r; };
    unsigned* cnt    = (unsigned*)alloc(N_NODES * 4);
    unsigned* cursor = (unsigned*)alloc(N_NODES * 4);
    int*      off    = (int*)alloc((N_NODES + 1) * 4);
    int*      csr    = (int*)alloc((size_t)N_EDGES * 4);
    float*    dinv   = (float*)alloc(N_NODES * 4);
    float*    g1     = (float*)alloc(N_NODES * 4);
    float*    sacc   = (float*)alloc(N_NODES * 4);
    float2*   sd     = (float2*)alloc((size_t)N_NODES * 8);
    float*    x2     = (float*)alloc((size_t)N_NODES * HID * 4);
    int*      gstart = (int*)alloc((N_GRAPHS + 1) * 4);

    hipMemsetAsync(cnt, 0, N_NODES * 4, stream);
    hipMemsetAsync(sacc, 0, N_NODES * 4, stream);

    const int TB = 256;
    int e4bl = (N_EDGES / 4 + TB - 1) / TB;
    int nbl  = (N_NODES + TB - 1) / TB;
    int wbl  = (N_NODES * 64 + TB - 1) / TB;   // wave-per-node kernels

    k_deg<<<e4bl, TB, 0, stream>>>((const int4*)dst, cnt);
    k_dinv<<<nbl, TB, 0, stream>>>(cnt, x, dinv, g1);
    k_scan<<<1, 1024, 0, stream>>>(cnt, off, cursor);
    k_scatter<<<e4bl, TB, 0, stream>>>((const int4*)src, (const int4*)dst, cursor, csr, g1, sacc);
    k_sd<<<nbl, TB, 0, stream>>>(sacc, dinv, x, sd);
    k_layer2<<<wbl, TB, 0, stream>>>(csr, off, sd, W1, b1, W2, b2, x2);
    k_bounds<<<nbl, TB, 0, stream>>>(batch, gstart);
    k_pool<<<N_GRAPHS, 256, 0, stream>>>(x2, sd, W1, b1, gstart, Wl, bl, out);
}